// Round 5
// baseline (113.825 us; speedup 1.0000x reference)
//
#include <hip/hip_runtime.h>
#include <hip/hip_bf16.h>
#include <cstddef>
#include <cstdint>

#define T_LEN 32
#define E_LEN 256
#define BATCH 16
#define DIM 512
#define HID 512
#define WROW 1024  // HID + DIM

#define TWO_LOG2E 2.8853900817779268f  // 2*log2(e)
#define LOG2E 1.4426950408889634f

typedef __attribute__((ext_vector_type(8))) short bf16x8;
typedef __attribute__((ext_vector_type(4))) float f32x4;

__device__ inline bf16x8 cvt8(float4 a, float4 b) {
    union { bf16x8 v; __hip_bfloat16 h[8]; } u;
    u.h[0] = __float2bfloat16(a.x); u.h[1] = __float2bfloat16(a.y);
    u.h[2] = __float2bfloat16(a.z); u.h[3] = __float2bfloat16(a.w);
    u.h[4] = __float2bfloat16(b.x); u.h[5] = __float2bfloat16(b.y);
    u.h[6] = __float2bfloat16(b.z); u.h[7] = __float2bfloat16(b.w);
    return u.v;
}

#define GPAD 8
#define GLDR (64 + GPAD)   // 72 halfwords per LDS row

// ---------------------------------------------------------------------------
// Fused projection GEMM (NT), f32 in -> bf16 MFMA -> exp2 -> out.
// Tile 64x64, BK=64, 256 threads, register-prefetched global loads,
// LDS double-buffered: one __syncthreads per K-step.
// ---------------------------------------------------------------------------
__global__ __launch_bounds__(256) void gemm_fused_k(
    const float* __restrict__ topic, const float* __restrict__ expo,
    const float* __restrict__ W, const float* __restrict__ battn,
    float* __restrict__ EPT, __hip_bfloat16* __restrict__ EPE) {
    __shared__ __align__(16) __hip_bfloat16 As[2][64 * GLDR];
    __shared__ __align__(16) __hip_bfloat16 Bs[2][64 * GLDR];
    const int tid = threadIdx.x;
    const int by = blockIdx.x >> 3;       // 0..71
    const int n0 = (blockIdx.x & 7) * 64;
    const float* A; const float* Wp; int m0;
    const bool isT = (by < 8);
    if (isT) { A = topic; Wp = W;       m0 = by * 64; }
    else     { A = expo;  Wp = W + DIM; m0 = (by - 8) * 64; }
    const int w = tid >> 6;
    const int lane = tid & 63;
    const int l15 = lane & 15;
    const int g = lane >> 4;
    const int srow = tid >> 2;   // 0..63
    const int sc = tid & 3;      // halfword chunks at sc*8 and sc*8+32

    f32x4 acc[4];
    const f32x4 z = {0.f, 0.f, 0.f, 0.f};
#pragma unroll
    for (int nt = 0; nt < 4; ++nt) acc[nt] = z;

    const float* ga = A + (size_t)(m0 + srow) * 512 + sc * 8;
    const float* gb = Wp + (size_t)(n0 + srow) * WROW + sc * 8;

    float4 a0 = *(const float4*)(ga);
    float4 a1 = *(const float4*)(ga + 4);
    float4 a2 = *(const float4*)(ga + 32);
    float4 a3 = *(const float4*)(ga + 36);
    float4 b0 = *(const float4*)(gb);
    float4 b1 = *(const float4*)(gb + 4);
    float4 b2 = *(const float4*)(gb + 32);
    float4 b3 = *(const float4*)(gb + 36);

    for (int kk = 0; kk < 8; ++kk) {
        const int cur = kk & 1;
        bf16x8 av0 = cvt8(a0, a1), av1 = cvt8(a2, a3);
        bf16x8 bv0 = cvt8(b0, b1), bv1 = cvt8(b2, b3);
        if (kk < 7) {  // prefetch next K-chunk while this one computes
            ga += 64; gb += 64;
            a0 = *(const float4*)(ga);
            a1 = *(const float4*)(ga + 4);
            a2 = *(const float4*)(ga + 32);
            a3 = *(const float4*)(ga + 36);
            b0 = *(const float4*)(gb);
            b1 = *(const float4*)(gb + 4);
            b2 = *(const float4*)(gb + 32);
            b3 = *(const float4*)(gb + 36);
        }
        *(bf16x8*)&As[cur][srow * GLDR + sc * 8] = av0;
        *(bf16x8*)&As[cur][srow * GLDR + sc * 8 + 32] = av1;
        *(bf16x8*)&Bs[cur][srow * GLDR + sc * 8] = bv0;
        *(bf16x8*)&Bs[cur][srow * GLDR + sc * 8 + 32] = bv1;
        __syncthreads();
#pragma unroll
        for (int s = 0; s < 2; ++s) {
            bf16x8 af = *(const bf16x8*)&As[cur][(w * 16 + l15) * GLDR + (s * 4 + g) * 8];
#pragma unroll
            for (int nt = 0; nt < 4; ++nt) {
                bf16x8 bf = *(const bf16x8*)&Bs[cur][(nt * 16 + l15) * GLDR + (s * 4 + g) * 8];
                acc[nt] = __builtin_amdgcn_mfma_f32_16x16x32_bf16(af, bf, acc[nt], 0, 0, 0);
            }
        }
    }
    if (isT) {
#pragma unroll
        for (int nt = 0; nt < 4; ++nt) {
            int n = n0 + nt * 16 + l15;
            float bv = battn[n];
#pragma unroll
            for (int r = 0; r < 4; ++r) {
                int m = m0 + w * 16 + g * 4 + r;
                EPT[(size_t)m * 512 + n] =
                    __builtin_amdgcn_exp2f((acc[nt][r] + bv) * TWO_LOG2E);
            }
        }
    } else {
#pragma unroll
        for (int nt = 0; nt < 4; ++nt) {
            int n = n0 + nt * 16 + l15;
#pragma unroll
            for (int r = 0; r < 4; ++r) {
                int m = m0 + w * 16 + g * 4 + r;
                EPE[(size_t)m * 512 + n] = __float2bfloat16(
                    __builtin_amdgcn_exp2f(acc[nt][r] * TWO_LOG2E));
            }
        }
    }
}

// ---------------------------------------------------------------------------
// MERGED: energies + new_exp. 512 blocks = (b, e-chunk of 8), 4 waves,
// wave owns 2 e's x ALL 32 t (4 t-chunks of 8) -> per-e P column completes
// in-block -> t-softmax + new_exp[b,e,:] = sum_t w_t*topic[t,b,:] fused.
// Eliminates the 512-block new_exp epilogue pass and the PT buffer;
// halves topic L2 traffic. Same per-CU quad count as before (2 blocks/CU).
// Quad math: validated 4-way reciprocal combining; reduction: validated
// packed butterfly (10 shuffles per (ei,tc), lane<8 holds t=tc*8+lane).
// P[b,t,e] still written for the new_topic kernel.
// ---------------------------------------------------------------------------
__global__ __launch_bounds__(256) void energies_exp_k(
    const float* __restrict__ EPT, const __hip_bfloat16* __restrict__ EPE,
    const float* __restrict__ v, const int* __restrict__ mask,
    const float* __restrict__ topic, float* __restrict__ P,
    float* __restrict__ out) {
    __shared__ __align__(16) float P_lds[8][32];  // [e_local][t]
    const int u = blockIdx.x;
    const int b = u >> 5;          // 16 b
    const int ech = u & 31;        // e-chunk of 8
    const int tid = threadIdx.x;
    const int lane = tid & 63;
    const int w = tid >> 6;
    const int h0 = lane * 8;
    const int e0 = ech * 8 + w * 2;
    const bool o1 = (lane & 1) != 0;
    const bool o2 = (lane & 2) != 0;
    const bool o4 = (lane & 4) != 0;

    int mk[2];
    mk[0] = mask[(e0 + 0) * BATCH + b];
    mk[1] = mask[(e0 + 1) * BATCH + b];

    float sv[8], sv2[4];
    {
        float4 v0 = *(const float4*)(v + h0);
        float4 v1 = *(const float4*)(v + h0 + 4);
        sv[0] = -2.f * v0.x; sv[1] = -2.f * v0.y; sv[2] = -2.f * v0.z; sv[3] = -2.f * v0.w;
        sv[4] = -2.f * v1.x; sv[5] = -2.f * v1.y; sv[6] = -2.f * v1.z; sv[7] = -2.f * v1.w;
        sv2[0] = sv[0] + sv[1]; sv2[1] = sv[2] + sv[3];
        sv2[2] = sv[4] + sv[5]; sv2[3] = sv[6] + sv[7];
    }
    // EPE rows for both e's (kept in registers across all 4 t-chunks)
    float pr2[2][8];
#pragma unroll
    for (int ei = 0; ei < 2; ++ei) {
        if (mk[ei] == 0) {
            union { bf16x8 v8; __hip_bfloat16 h[8]; } pv;
            pv.v8 = *(const bf16x8*)(EPE + ((size_t)((e0 + ei) * BATCH + b)) * HID + h0);
#pragma unroll
            for (int j = 0; j < 8; ++j) pr2[ei][j] = __bfloat162float(pv.h[j]);
        }
    }

    for (int tc = 0; tc < 4; ++tc) {
        float spt[8][8];
#pragma unroll
        for (int i = 0; i < 8; ++i) {
            const float* p = EPT + ((size_t)((tc * 8 + i) * BATCH + b)) * HID + h0;
            float4 p0 = *(const float4*)(p);
            float4 p1 = *(const float4*)(p + 4);
            spt[i][0] = p0.x; spt[i][1] = p0.y; spt[i][2] = p0.z; spt[i][3] = p0.w;
            spt[i][4] = p1.x; spt[i][5] = p1.y; spt[i][6] = p1.z; spt[i][7] = p1.w;
        }
#pragma unroll
        for (int ei = 0; ei < 2; ++ei) {
            const int e = e0 + ei;
            if (mk[ei] != 0) {  // wave-uniform
                if (lane < 8) {
                    P[((size_t)b * T_LEN + tc * 8 + lane) * E_LEN + e] = 1e-30f;
                    P_lds[w * 2 + ei][tc * 8 + lane] = 1e-30f;
                }
                continue;
            }
            float a[8] = {0.f, 0.f, 0.f, 0.f, 0.f, 0.f, 0.f, 0.f};
#pragma unroll
            for (int i = 0; i < 8; ++i) {
#pragma unroll
                for (int jq = 0; jq < 2; ++jq) {
                    const int j0 = jq * 4;
                    float a0 = spt[i][j0 + 0] * pr2[ei][j0 + 0];
                    float a1 = spt[i][j0 + 1] * pr2[ei][j0 + 1];
                    float a2 = spt[i][j0 + 2] * pr2[ei][j0 + 2];
                    float a3 = spt[i][j0 + 3] * pr2[ei][j0 + 3];
                    float u0 = a0 + 1.0f;
                    float u2 = a2 + 1.0f;
                    float d01 = fmaf(a1, u0, u0);           // (1+a0)(1+a1)
                    float d23 = fmaf(a3, u2, u2);           // (1+a2)(1+a3)
                    float n01 = fmaf(sv[j0 + 0], a1, fmaf(sv[j0 + 1], a0, sv2[jq * 2 + 0]));
                    float n23 = fmaf(sv[j0 + 2], a3, fmaf(sv[j0 + 3], a2, sv2[jq * 2 + 1]));
                    float nn = fmaf(n01, d23, n23 * d01);
                    float dd = d01 * d23;
                    a[i] = fmaf(nn, __builtin_amdgcn_rcpf(dd), a[i]);
                }
            }
            // Packed butterfly reduction (validated R4)
            float s, b0, b1, b2, b3, d0, d1, f;
            s = __shfl_xor(o1 ? a[0] : a[1], 1); b0 = (o1 ? a[1] : a[0]) + s;
            s = __shfl_xor(o1 ? a[2] : a[3], 1); b1 = (o1 ? a[3] : a[2]) + s;
            s = __shfl_xor(o1 ? a[4] : a[5], 1); b2 = (o1 ? a[5] : a[4]) + s;
            s = __shfl_xor(o1 ? a[6] : a[7], 1); b3 = (o1 ? a[7] : a[6]) + s;
            s = __shfl_xor(o2 ? b0 : b1, 2); d0 = (o2 ? b1 : b0) + s;
            s = __shfl_xor(o2 ? b2 : b3, 2); d1 = (o2 ? b3 : b2) + s;
            s = __shfl_xor(o4 ? d0 : d1, 4); f = (o4 ? d1 : d0) + s;
            f += __shfl_xor(f, 8);
            f += __shfl_xor(f, 16);
            f += __shfl_xor(f, 32);
            if (lane < 8) {
                float pe = __builtin_amdgcn_exp2f(f * LOG2E);
                P[((size_t)b * T_LEN + tc * 8 + lane) * E_LEN + e] = pe;
                P_lds[w * 2 + ei][tc * 8 + lane] = pe;
            }
        }
    }
    __syncthreads();  // P_lds complete (cheap: one barrier per block)

    // ---- fused new_exp for e0, e0+1 ----
    const int el0 = w * 2, el1 = w * 2 + 1;
    float s0 = 0.f, s1 = 0.f;
#pragma unroll
    for (int q = 0; q < 8; ++q) {  // uniform addr -> LDS broadcast
        float4 x = *(const float4*)&P_lds[el0][q * 4];
        s0 += (x.x + x.y) + (x.z + x.w);
        float4 y = *(const float4*)&P_lds[el1][q * 4];
        s1 += (y.x + y.y) + (y.z + y.w);
    }
    const float inv0 = __builtin_amdgcn_rcpf(s0);
    const float inv1 = __builtin_amdgcn_rcpf(s1);

    const int dA = lane * 4;        // d in [0,256)
    const int dB = 256 + lane * 4;  // d in [256,512)
    float4 aA0 = {0.f, 0.f, 0.f, 0.f}, aB0 = {0.f, 0.f, 0.f, 0.f};
    float4 aA1 = {0.f, 0.f, 0.f, 0.f}, aB1 = {0.f, 0.f, 0.f, 0.f};
#pragma unroll 2
    for (int tq = 0; tq < 8; ++tq) {
        float4 w0 = *(const float4*)&P_lds[el0][tq * 4];  // broadcast
        float4 w1 = *(const float4*)&P_lds[el1][tq * 4];
        w0.x *= inv0; w0.y *= inv0; w0.z *= inv0; w0.w *= inv0;
        w1.x *= inv1; w1.y *= inv1; w1.z *= inv1; w1.w *= inv1;
        float wt0[4] = {w0.x, w0.y, w0.z, w0.w};
        float wt1[4] = {w1.x, w1.y, w1.z, w1.w};
#pragma unroll
        for (int tt = 0; tt < 4; ++tt) {
            const int t = tq * 4 + tt;
            const float* tp = topic + ((size_t)t * BATCH + b) * DIM;
            float4 rA = *(const float4*)(tp + dA);
            float4 rB = *(const float4*)(tp + dB);
            aA0.x = fmaf(wt0[tt], rA.x, aA0.x); aA0.y = fmaf(wt0[tt], rA.y, aA0.y);
            aA0.z = fmaf(wt0[tt], rA.z, aA0.z); aA0.w = fmaf(wt0[tt], rA.w, aA0.w);
            aB0.x = fmaf(wt0[tt], rB.x, aB0.x); aB0.y = fmaf(wt0[tt], rB.y, aB0.y);
            aB0.z = fmaf(wt0[tt], rB.z, aB0.z); aB0.w = fmaf(wt0[tt], rB.w, aB0.w);
            aA1.x = fmaf(wt1[tt], rA.x, aA1.x); aA1.y = fmaf(wt1[tt], rA.y, aA1.y);
            aA1.z = fmaf(wt1[tt], rA.z, aA1.z); aA1.w = fmaf(wt1[tt], rA.w, aA1.w);
            aB1.x = fmaf(wt1[tt], rB.x, aB1.x); aB1.y = fmaf(wt1[tt], rB.y, aB1.y);
            aB1.z = fmaf(wt1[tt], rB.z, aB1.z); aB1.w = fmaf(wt1[tt], rB.w, aB1.w);
        }
    }
    float* oe0 = out + (size_t)BATCH * T_LEN * DIM + ((size_t)b * E_LEN + e0) * DIM;
    *(float4*)(oe0 + dA) = aA0;
    *(float4*)(oe0 + dB) = aB0;
    float* oe1 = oe0 + DIM;
    *(float4*)(oe1 + dA) = aA1;
    *(float4*)(oe1 + dB) = aB1;
}

// ---------------------------------------------------------------------------
// new_topic only, 256 blocks = (b, t-quad, d-half). Weights [e][4] in LDS so
// phase-2 reads ONE b128 broadcast per e (validated R4 layout).
// ---------------------------------------------------------------------------
__global__ __launch_bounds__(256) void newtopic_k(
    const float* __restrict__ P, const float* __restrict__ expo,
    float* __restrict__ out) {
    __shared__ __align__(16) float smem[5120];
    const int tid = threadIdx.x;
    const int lane = tid & 63;
    const int w = tid >> 6;
    const int q = blockIdx.x;         // [0,256)
    const int b = q >> 4;             // 16 b
    const int tq = (q >> 1) & 7;      // t-quad: t = tq*4 + {0..3}
    const int hf = q & 1;             // d-half
    // Phase 1: wave w computes softmax weights for t = tq*4 + w,
    // stored transposed [e][4] (one-time 32-way-conflict store, accepted).
    {
        const int bt = b * T_LEN + tq * 4 + w;
        float4 xv = *(const float4*)&P[(size_t)bt * E_LEN + lane * 4];
        float s = xv.x + xv.y + xv.z + xv.w;
#pragma unroll
        for (int off = 32; off; off >>= 1) s += __shfl_xor(s, off);
        float inv = __builtin_amdgcn_rcpf(s);
        smem[(lane * 4 + 0) * 4 + w] = xv.x * inv;
        smem[(lane * 4 + 1) * 4 + w] = xv.y * inv;
        smem[(lane * 4 + 2) * 4 + w] = xv.z * inv;
        smem[(lane * 4 + 3) * 4 + w] = xv.w * inv;
    }
    __syncthreads();
    // Phase 2: wave w handles e in [w*64, w*64+64); lane owns 4 d's;
    // ONE b128 weight broadcast per e.
    const int dl = lane * 4;
    const int dglob = hf * 256 + dl;
    float4 a0 = {0.f, 0.f, 0.f, 0.f};
    float4 a1 = {0.f, 0.f, 0.f, 0.f};
    float4 a2 = {0.f, 0.f, 0.f, 0.f};
    float4 a3 = {0.f, 0.f, 0.f, 0.f};
    const float* base = expo + (size_t)b * DIM + dglob;
    for (int ee = 0; ee < 64; ++ee) {
        const int e = w * 64 + ee;
        float4 rv = *(const float4*)(base + (size_t)e * BATCH * DIM);
        float4 wq = *(const float4*)&smem[e * 4];  // uniform addr -> broadcast
        a0.x = fmaf(wq.x, rv.x, a0.x); a0.y = fmaf(wq.x, rv.y, a0.y);
        a0.z = fmaf(wq.x, rv.z, a0.z); a0.w = fmaf(wq.x, rv.w, a0.w);
        a1.x = fmaf(wq.y, rv.x, a1.x); a1.y = fmaf(wq.y, rv.y, a1.y);
        a1.z = fmaf(wq.y, rv.z, a1.z); a1.w = fmaf(wq.y, rv.w, a1.w);
        a2.x = fmaf(wq.z, rv.x, a2.x); a2.y = fmaf(wq.z, rv.y, a2.y);
        a2.z = fmaf(wq.z, rv.z, a2.z); a2.w = fmaf(wq.z, rv.w, a2.w);
        a3.x = fmaf(wq.w, rv.x, a3.x); a3.y = fmaf(wq.w, rv.y, a3.y);
        a3.z = fmaf(wq.w, rv.z, a3.z); a3.w = fmaf(wq.w, rv.w, a3.w);
    }
    // partials: [wave][t][256 d]
    *(float4*)&smem[1024 + (w * 4 + 0) * 256 + dl] = a0;
    *(float4*)&smem[1024 + (w * 4 + 1) * 256 + dl] = a1;
    *(float4*)&smem[1024 + (w * 4 + 2) * 256 + dl] = a2;
    *(float4*)&smem[1024 + (w * 4 + 3) * 256 + dl] = a3;
    __syncthreads();
    // Phase 3: 256 threads x 4 outputs: (tt, d=tid)
#pragma unroll
    for (int tt = 0; tt < 4; ++tt) {
        float sum = smem[1024 + (0 * 4 + tt) * 256 + tid] +
                    smem[1024 + (1 * 4 + tt) * 256 + tid] +
                    smem[1024 + (2 * 4 + tt) * 256 + tid] +
                    smem[1024 + (3 * 4 + tt) * 256 + tid];
        out[((size_t)b * T_LEN + tq * 4 + tt) * DIM + hf * 256 + tid] = sum;
    }
}

extern "C" void kernel_launch(void* const* d_in, const int* in_sizes, int n_in,
                              void* d_out, int out_size, void* d_ws, size_t ws_size,
                              hipStream_t stream) {
    const float* topic = (const float*)d_in[0];   // [T,B,D]
    const float* expo  = (const float*)d_in[1];   // [E,B,D]
    const int*   mask  = (const int*)d_in[2];     // [E,B]
    const float* W     = (const float*)d_in[3];   // [H, H+D]
    const float* battn = (const float*)d_in[4];   // [H]
    const float* vsc   = (const float*)d_in[5];   // [1,H]
    float* out = (float*)d_out;                   // new_topic [B,T,D] ++ new_exp [B,E,D]

    float* EPT = (float*)d_ws;                                // [512,512] f32, 1 MB
    __hip_bfloat16* EPE = (__hip_bfloat16*)(EPT + 512 * 512); // [4096,512] bf16, 4 MB
    float* P = (float*)(EPE + (size_t)4096 * 512);            // [B,T,E] f32, 0.5 MB

    gemm_fused_k<<<576, 256, 0, stream>>>(topic, expo, W, battn, EPT, EPE);
    energies_exp_k<<<512, 256, 0, stream>>>(EPT, EPE, vsc, mask, topic, P, out);
    newtopic_k<<<256, 256, 0, stream>>>(P, expo, out);
}

// Round 6
// 112.179 us; speedup vs baseline: 1.0147x; 1.0147x over previous
//
#include <hip/hip_runtime.h>
#include <hip/hip_bf16.h>
#include <cstddef>
#include <cstdint>

#define T_LEN 32
#define E_LEN 256
#define BATCH 16
#define DIM 512
#define HID 512
#define WROW 1024  // HID + DIM

#define TWO_LOG2E 2.8853900817779268f  // 2*log2(e)
#define LOG2E 1.4426950408889634f

typedef __attribute__((ext_vector_type(8))) short bf16x8;
typedef __attribute__((ext_vector_type(4))) float f32x4;

__device__ inline bf16x8 cvt8(float4 a, float4 b) {
    union { bf16x8 v; __hip_bfloat16 h[8]; } u;
    u.h[0] = __float2bfloat16(a.x); u.h[1] = __float2bfloat16(a.y);
    u.h[2] = __float2bfloat16(a.z); u.h[3] = __float2bfloat16(a.w);
    u.h[4] = __float2bfloat16(b.x); u.h[5] = __float2bfloat16(b.y);
    u.h[6] = __float2bfloat16(b.z); u.h[7] = __float2bfloat16(b.w);
    return u.v;
}

#define GPAD 8
#define GLDR (64 + GPAD)   // 72 halfwords per LDS row

// ---------------------------------------------------------------------------
// Fused projection GEMM (NT), f32 in -> bf16 MFMA -> exp2 -> out.
// Tile 64x64, BK=64, 256 threads, register-prefetched global loads,
// LDS double-buffered: one __syncthreads per K-step.
// ---------------------------------------------------------------------------
__global__ __launch_bounds__(256) void gemm_fused_k(
    const float* __restrict__ topic, const float* __restrict__ expo,
    const float* __restrict__ W, const float* __restrict__ battn,
    float* __restrict__ EPT, __hip_bfloat16* __restrict__ EPE) {
    __shared__ __align__(16) __hip_bfloat16 As[2][64 * GLDR];
    __shared__ __align__(16) __hip_bfloat16 Bs[2][64 * GLDR];
    const int tid = threadIdx.x;
    const int by = blockIdx.x >> 3;       // 0..71
    const int n0 = (blockIdx.x & 7) * 64;
    const float* A; const float* Wp; int m0;
    const bool isT = (by < 8);
    if (isT) { A = topic; Wp = W;       m0 = by * 64; }
    else     { A = expo;  Wp = W + DIM; m0 = (by - 8) * 64; }
    const int w = tid >> 6;
    const int lane = tid & 63;
    const int l15 = lane & 15;
    const int g = lane >> 4;
    const int srow = tid >> 2;   // 0..63
    const int sc = tid & 3;      // halfword chunks at sc*8 and sc*8+32

    f32x4 acc[4];
    const f32x4 z = {0.f, 0.f, 0.f, 0.f};
#pragma unroll
    for (int nt = 0; nt < 4; ++nt) acc[nt] = z;

    const float* ga = A + (size_t)(m0 + srow) * 512 + sc * 8;
    const float* gb = Wp + (size_t)(n0 + srow) * WROW + sc * 8;

    float4 a0 = *(const float4*)(ga);
    float4 a1 = *(const float4*)(ga + 4);
    float4 a2 = *(const float4*)(ga + 32);
    float4 a3 = *(const float4*)(ga + 36);
    float4 b0 = *(const float4*)(gb);
    float4 b1 = *(const float4*)(gb + 4);
    float4 b2 = *(const float4*)(gb + 32);
    float4 b3 = *(const float4*)(gb + 36);

    for (int kk = 0; kk < 8; ++kk) {
        const int cur = kk & 1;
        bf16x8 av0 = cvt8(a0, a1), av1 = cvt8(a2, a3);
        bf16x8 bv0 = cvt8(b0, b1), bv1 = cvt8(b2, b3);
        if (kk < 7) {  // prefetch next K-chunk while this one computes
            ga += 64; gb += 64;
            a0 = *(const float4*)(ga);
            a1 = *(const float4*)(ga + 4);
            a2 = *(const float4*)(ga + 32);
            a3 = *(const float4*)(ga + 36);
            b0 = *(const float4*)(gb);
            b1 = *(const float4*)(gb + 4);
            b2 = *(const float4*)(gb + 32);
            b3 = *(const float4*)(gb + 36);
        }
        *(bf16x8*)&As[cur][srow * GLDR + sc * 8] = av0;
        *(bf16x8*)&As[cur][srow * GLDR + sc * 8 + 32] = av1;
        *(bf16x8*)&Bs[cur][srow * GLDR + sc * 8] = bv0;
        *(bf16x8*)&Bs[cur][srow * GLDR + sc * 8 + 32] = bv1;
        __syncthreads();
#pragma unroll
        for (int s = 0; s < 2; ++s) {
            bf16x8 af = *(const bf16x8*)&As[cur][(w * 16 + l15) * GLDR + (s * 4 + g) * 8];
#pragma unroll
            for (int nt = 0; nt < 4; ++nt) {
                bf16x8 bf = *(const bf16x8*)&Bs[cur][(nt * 16 + l15) * GLDR + (s * 4 + g) * 8];
                acc[nt] = __builtin_amdgcn_mfma_f32_16x16x32_bf16(af, bf, acc[nt], 0, 0, 0);
            }
        }
    }
    if (isT) {
#pragma unroll
        for (int nt = 0; nt < 4; ++nt) {
            int n = n0 + nt * 16 + l15;
            float bv = battn[n];
#pragma unroll
            for (int r = 0; r < 4; ++r) {
                int m = m0 + w * 16 + g * 4 + r;
                EPT[(size_t)m * 512 + n] =
                    __builtin_amdgcn_exp2f((acc[nt][r] + bv) * TWO_LOG2E);
            }
        }
    } else {
#pragma unroll
        for (int nt = 0; nt < 4; ++nt) {
            int n = n0 + nt * 16 + l15;
#pragma unroll
            for (int r = 0; r < 4; ++r) {
                int m = m0 + w * 16 + g * 4 + r;
                EPE[(size_t)m * 512 + n] = __float2bfloat16(
                    __builtin_amdgcn_exp2f(acc[nt][r] * TWO_LOG2E));
            }
        }
    }
}

// ---------------------------------------------------------------------------
// Energies -> P[b,t,e] and PT[b,e,t] = exp(energy - const); masked -> 1e-30.
// 4-way reciprocal combining: 15 VALU + 1 rcp per quad.
// Packed butterfly reduction: 10 shuffles/ei (R4-validated win, -2.45us).
// Wave: 4 e's x 8 t's; block = (b, 8 t's, 16 e's); grid 1024.
// ---------------------------------------------------------------------------
__global__ __launch_bounds__(256) void energies_k(
    const float* __restrict__ EPT, const __hip_bfloat16* __restrict__ EPE,
    const float* __restrict__ v, const int* __restrict__ mask,
    float* __restrict__ P, float* __restrict__ PT) {
    const int u = blockIdx.x;
    const int b = u & 15;
    const int tg = (u >> 4) & 3;   // t = tg*8 + i
    const int ech = u >> 6;        // e base = ech*16
    const int tid = threadIdx.x;
    const int lane = tid & 63;
    const int w = tid >> 6;
    const int h0 = lane * 8;
    const int e0 = ech * 16 + w * 4;
    const bool o1 = (lane & 1) != 0;
    const bool o2 = (lane & 2) != 0;
    const bool o4 = (lane & 4) != 0;

    int mk[4];
#pragma unroll
    for (int ei = 0; ei < 4; ++ei) mk[ei] = mask[(e0 + ei) * BATCH + b];

    float sv[8], sv2[4], spt[8][8];
    {
        float4 v0 = *(const float4*)(v + h0);
        float4 v1 = *(const float4*)(v + h0 + 4);
        sv[0] = -2.f * v0.x; sv[1] = -2.f * v0.y; sv[2] = -2.f * v0.z; sv[3] = -2.f * v0.w;
        sv[4] = -2.f * v1.x; sv[5] = -2.f * v1.y; sv[6] = -2.f * v1.z; sv[7] = -2.f * v1.w;
        sv2[0] = sv[0] + sv[1]; sv2[1] = sv[2] + sv[3];
        sv2[2] = sv[4] + sv[5]; sv2[3] = sv[6] + sv[7];
#pragma unroll
        for (int i = 0; i < 8; ++i) {
            const float* p = EPT + ((size_t)((tg * 8 + i) * BATCH + b)) * HID + h0;
            float4 p0 = *(const float4*)(p);
            float4 p1 = *(const float4*)(p + 4);
            spt[i][0] = p0.x; spt[i][1] = p0.y; spt[i][2] = p0.z; spt[i][3] = p0.w;
            spt[i][4] = p1.x; spt[i][5] = p1.y; spt[i][6] = p1.z; spt[i][7] = p1.w;
        }
    }
#pragma unroll
    for (int ei = 0; ei < 4; ++ei) {
        const int e = e0 + ei;
        if (mk[ei] != 0) {  // wave-uniform skip
            if (lane < 8) {
                P[((size_t)b * T_LEN + tg * 8 + lane) * E_LEN + e] = 1e-30f;
                PT[((size_t)b * E_LEN + e) * T_LEN + tg * 8 + lane] = 1e-30f;
            }
            continue;
        }
        union { bf16x8 v8; __hip_bfloat16 h[8]; } pv;
        pv.v8 = *(const bf16x8*)(EPE + ((size_t)(e * BATCH + b)) * HID + h0);
        float pr[8];
#pragma unroll
        for (int j = 0; j < 8; ++j) pr[j] = __bfloat162float(pv.h[j]);
        float a[8] = {0.f, 0.f, 0.f, 0.f, 0.f, 0.f, 0.f, 0.f};
#pragma unroll
        for (int i = 0; i < 8; ++i) {
#pragma unroll
            for (int jq = 0; jq < 2; ++jq) {
                const int j0 = jq * 4;
                float a0 = spt[i][j0 + 0] * pr[j0 + 0];
                float a1 = spt[i][j0 + 1] * pr[j0 + 1];
                float a2 = spt[i][j0 + 2] * pr[j0 + 2];
                float a3 = spt[i][j0 + 3] * pr[j0 + 3];
                float u0 = a0 + 1.0f;
                float u2 = a2 + 1.0f;
                float d01 = fmaf(a1, u0, u0);           // (1+a0)(1+a1)
                float d23 = fmaf(a3, u2, u2);           // (1+a2)(1+a3)
                float n01 = fmaf(sv[j0 + 0], a1, fmaf(sv[j0 + 1], a0, sv2[jq * 2 + 0]));
                float n23 = fmaf(sv[j0 + 2], a3, fmaf(sv[j0 + 3], a2, sv2[jq * 2 + 1]));
                float nn = fmaf(n01, d23, n23 * d01);
                float dd = d01 * d23;
                a[i] = fmaf(nn, __builtin_amdgcn_rcpf(dd), a[i]);
            }
        }
        // Packed butterfly: level 1 (xor 1) — 8 accs -> 4, 4 shuffles
        float s, b0, b1, b2, b3, d0, d1, f;
        s = __shfl_xor(o1 ? a[0] : a[1], 1); b0 = (o1 ? a[1] : a[0]) + s;
        s = __shfl_xor(o1 ? a[2] : a[3], 1); b1 = (o1 ? a[3] : a[2]) + s;
        s = __shfl_xor(o1 ? a[4] : a[5], 1); b2 = (o1 ? a[5] : a[4]) + s;
        s = __shfl_xor(o1 ? a[6] : a[7], 1); b3 = (o1 ? a[7] : a[6]) + s;
        // level 2 (xor 2) — 4 -> 2
        s = __shfl_xor(o2 ? b0 : b1, 2); d0 = (o2 ? b1 : b0) + s;
        s = __shfl_xor(o2 ? b2 : b3, 2); d1 = (o2 ? b3 : b2) + s;
        // level 3 (xor 4) — 2 -> 1; lane now holds t = lane&7 partial
        s = __shfl_xor(o4 ? d0 : d1, 4); f = (o4 ? d1 : d0) + s;
        // levels 4-6: plain adds complete the 64-lane sum
        f += __shfl_xor(f, 8);
        f += __shfl_xor(f, 16);
        f += __shfl_xor(f, 32);
        if (lane < 8) {
            float pe = __builtin_amdgcn_exp2f(f * LOG2E);
            P[((size_t)b * T_LEN + tg * 8 + lane) * E_LEN + e] = pe;
            PT[((size_t)b * E_LEN + e) * T_LEN + tg * 8 + lane] = pe;
        }
    }
}

// ---------------------------------------------------------------------------
// Fused epilogue on P/PT, 768 blocks (R4-validated structure).
// blocks [0,512): new_exp, block=(b, e-chunk of 16, d-half). Softmax reads
//   the coalesced PT row; weights staged in LDS [e_local][32]; main loop
//   reads per-t-quad b128 broadcasts.
// blocks [512,768): new_topic, block=(b, t-quad, d-half): weights stored
//   [e][4] so phase-2 reads ONE b128 broadcast per e.
// ---------------------------------------------------------------------------
__global__ __launch_bounds__(256) void epilogue_k(
    const float* __restrict__ P, const float* __restrict__ PT,
    const float* __restrict__ topic,
    const float* __restrict__ expo, float* __restrict__ out) {
    __shared__ __align__(16) float smem[5120];
    const int tid = threadIdx.x;
    const int lane = tid & 63;
    const int w = tid >> 6;
    if (blockIdx.x < 512) {
        // ---- new_exp ----
        const int b = blockIdx.x >> 5;
        const int ech = (blockIdx.x >> 1) & 15;
        const int hf = blockIdx.x & 1;
        const int e0 = ech * 16 + w * 4;
        // weights: wsm[e_local][32], e_local = w*4+ei
#pragma unroll
        for (int ei = 0; ei < 4; ++ei) {
            const int e = e0 + ei;
            float x = 0.f;
            if (lane < T_LEN)
                x = PT[((size_t)b * E_LEN + e) * T_LEN + lane];  // coalesced row
            float s = x;
#pragma unroll
            for (int off = 32; off; off >>= 1) s += __shfl_xor(s, off);
            float wv = x * __builtin_amdgcn_rcpf(s);
            if (lane < T_LEN) smem[(w * 4 + ei) * 32 + lane] = wv;
        }
        __syncthreads();
        const int d0 = hf * 256 + lane * 4;
        float4 acc[4];
#pragma unroll
        for (int ei = 0; ei < 4; ++ei) acc[ei] = {0.f, 0.f, 0.f, 0.f};
#pragma unroll 2
        for (int tq = 0; tq < 8; ++tq) {
            float wqa[4][4];
#pragma unroll
            for (int ei = 0; ei < 4; ++ei) {
                float4 q = *(const float4*)&smem[(w * 4 + ei) * 32 + tq * 4];  // broadcast
                wqa[ei][0] = q.x; wqa[ei][1] = q.y; wqa[ei][2] = q.z; wqa[ei][3] = q.w;
            }
#pragma unroll
            for (int tt = 0; tt < 4; ++tt) {
                const int t = tq * 4 + tt;
                float4 r = *(const float4*)(topic + ((size_t)t * BATCH + b) * DIM + d0);
#pragma unroll
                for (int ei = 0; ei < 4; ++ei) {
                    acc[ei].x = fmaf(wqa[ei][tt], r.x, acc[ei].x);
                    acc[ei].y = fmaf(wqa[ei][tt], r.y, acc[ei].y);
                    acc[ei].z = fmaf(wqa[ei][tt], r.z, acc[ei].z);
                    acc[ei].w = fmaf(wqa[ei][tt], r.w, acc[ei].w);
                }
            }
        }
#pragma unroll
        for (int ei = 0; ei < 4; ++ei) {
            float* o = out + (size_t)BATCH * T_LEN * DIM +
                       ((size_t)b * E_LEN + e0 + ei) * DIM + d0;
            *(float4*)o = acc[ei];
        }
    } else {
        // ---- new_topic (t-quad) ----
        const int q = blockIdx.x - 512;   // [0,256)
        const int b = q >> 4;             // 16 b
        const int tq = (q >> 1) & 7;      // t-quad: t = tq*4 + {0..3}
        const int hf = q & 1;             // d-half
        // Phase 1: wave w computes softmax weights for t = tq*4 + w,
        // stored transposed [e][4] (one-time 32-way-conflict store, accepted).
        {
            const int bt = b * T_LEN + tq * 4 + w;
            float4 xv = *(const float4*)&P[(size_t)bt * E_LEN + lane * 4];
            float s = xv.x + xv.y + xv.z + xv.w;
#pragma unroll
            for (int off = 32; off; off >>= 1) s += __shfl_xor(s, off);
            float inv = __builtin_amdgcn_rcpf(s);
            smem[(lane * 4 + 0) * 4 + w] = xv.x * inv;
            smem[(lane * 4 + 1) * 4 + w] = xv.y * inv;
            smem[(lane * 4 + 2) * 4 + w] = xv.z * inv;
            smem[(lane * 4 + 3) * 4 + w] = xv.w * inv;
        }
        __syncthreads();
        // Phase 2: wave w handles e in [w*64, w*64+64); lane owns 4 d's;
        // ONE b128 weight broadcast per e. unroll 4 -> more loads in flight
        // (this branch runs at ~1 block/CU; latency-exposed).
        const int dl = lane * 4;
        const int dglob = hf * 256 + dl;
        float4 a0 = {0.f, 0.f, 0.f, 0.f};
        float4 a1 = {0.f, 0.f, 0.f, 0.f};
        float4 a2 = {0.f, 0.f, 0.f, 0.f};
        float4 a3 = {0.f, 0.f, 0.f, 0.f};
        const float* base = expo + (size_t)b * DIM + dglob +
                            (size_t)(w * 64) * BATCH * DIM;
#pragma unroll 4
        for (int ee = 0; ee < 64; ++ee) {
            const int e = w * 64 + ee;
            float4 rv = *(const float4*)(base + (size_t)ee * BATCH * DIM);
            float4 wq = *(const float4*)&smem[e * 4];  // uniform addr -> broadcast
            a0.x = fmaf(wq.x, rv.x, a0.x); a0.y = fmaf(wq.x, rv.y, a0.y);
            a0.z = fmaf(wq.x, rv.z, a0.z); a0.w = fmaf(wq.x, rv.w, a0.w);
            a1.x = fmaf(wq.y, rv.x, a1.x); a1.y = fmaf(wq.y, rv.y, a1.y);
            a1.z = fmaf(wq.y, rv.z, a1.z); a1.w = fmaf(wq.y, rv.w, a1.w);
            a2.x = fmaf(wq.z, rv.x, a2.x); a2.y = fmaf(wq.z, rv.y, a2.y);
            a2.z = fmaf(wq.z, rv.z, a2.z); a2.w = fmaf(wq.z, rv.w, a2.w);
            a3.x = fmaf(wq.w, rv.x, a3.x); a3.y = fmaf(wq.w, rv.y, a3.y);
            a3.z = fmaf(wq.w, rv.z, a3.z); a3.w = fmaf(wq.w, rv.w, a3.w);
        }
        // partials: [wave][t][256 d]
        *(float4*)&smem[1024 + (w * 4 + 0) * 256 + dl] = a0;
        *(float4*)&smem[1024 + (w * 4 + 1) * 256 + dl] = a1;
        *(float4*)&smem[1024 + (w * 4 + 2) * 256 + dl] = a2;
        *(float4*)&smem[1024 + (w * 4 + 3) * 256 + dl] = a3;
        __syncthreads();
        // Phase 3: 256 threads x 4 outputs: (tt, d=tid)
#pragma unroll
        for (int tt = 0; tt < 4; ++tt) {
            float sum = smem[1024 + (0 * 4 + tt) * 256 + tid] +
                        smem[1024 + (1 * 4 + tt) * 256 + tid] +
                        smem[1024 + (2 * 4 + tt) * 256 + tid] +
                        smem[1024 + (3 * 4 + tt) * 256 + tid];
            out[((size_t)b * T_LEN + tq * 4 + tt) * DIM + hf * 256 + tid] = sum;
        }
    }
}

extern "C" void kernel_launch(void* const* d_in, const int* in_sizes, int n_in,
                              void* d_out, int out_size, void* d_ws, size_t ws_size,
                              hipStream_t stream) {
    const float* topic = (const float*)d_in[0];   // [T,B,D]
    const float* expo  = (const float*)d_in[1];   // [E,B,D]
    const int*   mask  = (const int*)d_in[2];     // [E,B]
    const float* W     = (const float*)d_in[3];   // [H, H+D]
    const float* battn = (const float*)d_in[4];   // [H]
    const float* vsc   = (const float*)d_in[5];   // [1,H]
    float* out = (float*)d_out;                   // new_topic [B,T,D] ++ new_exp [B,E,D]

    float* EPT = (float*)d_ws;                                // [512,512] f32, 1 MB
    __hip_bfloat16* EPE = (__hip_bfloat16*)(EPT + 512 * 512); // [4096,512] bf16, 4 MB
    float* P  = (float*)(EPE + (size_t)4096 * 512);           // [B,T,E] f32, 0.5 MB
    float* PT = P + (size_t)BATCH * T_LEN * E_LEN;            // [B,E,T] f32, 0.5 MB

    gemm_fused_k<<<576, 256, 0, stream>>>(topic, expo, W, battn, EPT, EPE);
    energies_k<<<1024, 256, 0, stream>>>(EPT, EPE, vsc, mask, P, PT);
    epilogue_k<<<768, 256, 0, stream>>>(P, PT, topic, expo, out);
}